// Round 10
// baseline (197.037 us; speedup 1.0000x reference)
//
#include <hip/hip_runtime.h>

#define NN 4096
#define HEADS 8
#define DD 64
#define QKD 512

typedef __attribute__((ext_vector_type(8))) short short8;
typedef __attribute__((ext_vector_type(4))) float f32x4;
typedef __attribute__((ext_vector_type(4))) float float4v;
typedef __attribute__((ext_vector_type(4))) int int4v;
typedef unsigned int u32;
typedef unsigned short u16;
typedef unsigned long long u64;

union U8 { u16 u[8]; short8 s; };
union U4 { u32 u[4]; short8 s; };

__device__ __forceinline__ u16 f2bf(float f) {
  u32 u = __float_as_uint(f);
  u += 0x7fffu + ((u >> 16) & 1u);   // RNE
  return (u16)(u >> 16);
}

__device__ __forceinline__ u32 cvtpk(float lo, float hi) {   // bf16(lo) | bf16(hi)<<16, RNE
  u32 d;
  asm("v_cvt_pk_bf16_f32 %0, %1, %2" : "=v"(d) : "v"(lo), "v"(hi));
  return d;
}

#define GLL(src, dst) __builtin_amdgcn_global_load_lds( \
    (const __attribute__((address_space(1))) void*)(src), \
    (__attribute__((address_space(3))) void*)(dst), 16, 0, 0)

// ============================================================================
// Fused prepass [R8 verbatim] (single launch, 5120 blocks x 256):
//   b in [0,4096):      adj row b -> TRANSPOSED bitmask At[tile*4096 + row] (u64)
//   b in [4096,4608):   x2 -> K bf16 tile images (pre-swizzled)
//   b in [4608,5120):   v  -> V^T bf16 tile images (pre-swizzled)
// K tile (h,kb), 8 KB:  I[off] = K[kb*64+kr][h*64+d],  off = kr*128 + (d*2 ^ ((kr&7)<<4))
// V tile (h,kb), 8 KB:  I[off] = V[kb*64+k ][h*64+vd], off = vd*128 + (k*2 ^ ((vd&7)<<4))
// ============================================================================
__global__ __launch_bounds__(256) void prepass_fused(
    const float* __restrict__ x2, const float* __restrict__ v,
    const int* __restrict__ adj,
    u16* __restrict__ Kbt, u16* __restrict__ Vbt, u64* __restrict__ At)
{
  __shared__ u16 Vtmp[64][80];
  const int b = blockIdx.x;
  const int t = threadIdx.x;

  if (b < 4096) {                      // ---------------- ADJ pack (1 row/block)
    const int row = b;
    const int* src = adj + (size_t)row * NN;
    int4v a0 = *(const int4v*)(src + t * 16);
    int4v a1 = *(const int4v*)(src + t * 16 + 4);
    int4v a2 = *(const int4v*)(src + t * 16 + 8);
    int4v a3 = *(const int4v*)(src + t * 16 + 12);
    u32 bits =
        (u32)(a0.x > 0)         | ((u32)(a0.y > 0) << 1)  |
        ((u32)(a0.z > 0) << 2)  | ((u32)(a0.w > 0) << 3)  |
        ((u32)(a1.x > 0) << 4)  | ((u32)(a1.y > 0) << 5)  |
        ((u32)(a1.z > 0) << 6)  | ((u32)(a1.w > 0) << 7)  |
        ((u32)(a2.x > 0) << 8)  | ((u32)(a2.y > 0) << 9)  |
        ((u32)(a2.z > 0) << 10) | ((u32)(a2.w > 0) << 11) |
        ((u32)(a3.x > 0) << 12) | ((u32)(a3.y > 0) << 13) |
        ((u32)(a3.z > 0) << 14) | ((u32)(a3.w > 0) << 15);
    unsigned char* AB = (unsigned char*)Vtmp;
    *(u16*)(AB + t * 2) = (u16)bits;
    __syncthreads();
    if (t < 64) {
      u64 m = *(const u64*)(AB + t * 8);      // word t = cols 64t..64t+63 (LE)
      At[(size_t)t * NN + row] = m;           // TRANSPOSED: [tile][row]
    }
  } else if (b < 4608) {               // ---------------- K tiles
    const int j = b - 4096;
    const int h = j >> 6, kb = j & 63;
    u16* dst = Kbt + (size_t)j * 4096;
    #pragma unroll
    for (int i = 0; i < 2; i++) {
      int c = t + i * 256;
      int off = c * 16;
      int kr = off >> 7;
      int db = (off & 127) ^ ((kr & 7) << 4);
      int d0 = db >> 1;
      const float* p = x2 + (size_t)(kb * 64 + kr) * QKD + h * DD + d0;
      float4v a0 = *(const float4v*)p;
      float4v a1 = *(const float4v*)(p + 4);
      U8 r;
      r.u[0] = f2bf(a0.x); r.u[1] = f2bf(a0.y); r.u[2] = f2bf(a0.z); r.u[3] = f2bf(a0.w);
      r.u[4] = f2bf(a1.x); r.u[5] = f2bf(a1.y); r.u[6] = f2bf(a1.z); r.u[7] = f2bf(a1.w);
      *(short8*)((char*)dst + off) = r.s;
    }
  } else {                             // ---------------- V tiles (transpose via LDS)
    const int bb = b - 4608;
    const int h = bb >> 6, kb = bb & 63;
    {
      int k = t >> 2, j0 = (t & 3) * 16;
      const float* p = v + (size_t)(kb * 64 + k) * QKD + h * DD + j0;
      float4v a0 = *(const float4v*)p;
      float4v a1 = *(const float4v*)(p + 4);
      float4v a2 = *(const float4v*)(p + 8);
      float4v a3 = *(const float4v*)(p + 12);
      U8 r0, r1;
      r0.u[0] = f2bf(a0.x); r0.u[1] = f2bf(a0.y); r0.u[2] = f2bf(a0.z); r0.u[3] = f2bf(a0.w);
      r0.u[4] = f2bf(a1.x); r0.u[5] = f2bf(a1.y); r0.u[6] = f2bf(a1.z); r0.u[7] = f2bf(a1.w);
      r1.u[0] = f2bf(a2.x); r1.u[1] = f2bf(a2.y); r1.u[2] = f2bf(a2.z); r1.u[3] = f2bf(a2.w);
      r1.u[4] = f2bf(a3.x); r1.u[5] = f2bf(a3.y); r1.u[6] = f2bf(a3.z); r1.u[7] = f2bf(a3.w);
      *(short8*)(&Vtmp[k][j0]) = r0.s;
      *(short8*)(&Vtmp[k][j0 + 8]) = r1.s;
    }
    __syncthreads();
    u16* dst = Vbt + (size_t)bb * 4096;
    #pragma unroll
    for (int i = 0; i < 2; i++) {
      int c = t + i * 256;
      int off = c * 16;
      int vd = off >> 7;
      int kbyte = (off & 127) ^ ((vd & 7) << 4);
      int k0 = kbyte >> 1;
      U8 r;
      #pragma unroll
      for (int jj = 0; jj < 8; jj++) r.u[jj] = Vtmp[k0 + jj][vd];
      *(short8*)((char*)dst + off) = r.s;
    }
  }
}

// ============================================================================
// Main fused kernel. R8 math body, software-pipelined one K-tile ahead:
//   iter i: stage K(i+2) [3-slot ring] + V(i) [single buf, staged-at-top];
//           softmax(i) on CARRIED st; QK^T(i+1) -> stN (MFMA hides under VALU);
//           mid-barrier (V ready); PV(i); end-barrier (protects V overwrite).
// Slot lifetimes: K slot s=(i)%3 written at iter i-2, read (QK^T) at iter i-1,
// next write at i+1 — one barrier in between each. V written at top of i,
// read after mid-barrier of i, freed at end-barrier of i.
// Grid 512 (h = b&7: per-XCD single head), 512 thr = 4 q-waves x 2 k-parities.
// ============================================================================
__global__ __launch_bounds__(512, 4) void attn_fast(
    const float* __restrict__ x1,
    const u64* __restrict__ At,
    const u16* __restrict__ Kbt, const u16* __restrict__ Vbt,
    float* __restrict__ out)
{
  __shared__ u16 KL[2][3][4096];   // [kpar][ring slot][8KB tile image]  48 KB
  __shared__ u16 VL[2][4096];      // [kpar][8KB tile image]             16 KB

  const int b = blockIdx.x;
  const int h = b & 7;             // XCD-head affinity
  const int qt = b >> 3;
  const int t = threadIdx.x;
  const int w = t >> 6;
  const int lane = t & 63;
  const int g = lane >> 4;
  const int qi = lane & 15;
  const int qh = w & 3;
  const int kpar = w >> 2;
  const int qrow = qt * 64 + qh * 16 + qi;

  const u16* Ktiles = Kbt + (size_t)h * 64 * 4096;
  const u16* Vtiles = Vbt + (size_t)h * 64 * 4096;

  const float SCL = 0.125f * 1.4426950408889634f;
  short8 qfrag[2];
  #pragma unroll
  for (int dc = 0; dc < 2; dc++) {
    const float* p = x1 + (size_t)qrow * QKD + h * DD + dc * 32 + g * 8;
    float4v a = *(const float4v*)p;
    float4v c = *(const float4v*)(p + 4);
    U8 r;
    r.u[0] = f2bf(a.x * SCL); r.u[1] = f2bf(a.y * SCL);
    r.u[2] = f2bf(a.z * SCL); r.u[3] = f2bf(a.w * SCL);
    r.u[4] = f2bf(c.x * SCL); r.u[5] = f2bf(c.y * SCL);
    r.u[6] = f2bf(c.z * SCL); r.u[7] = f2bf(c.w * SCL);
    qfrag[dc] = r.s;
  }

  const f32x4 zero = {0.f, 0.f, 0.f, 0.f};
  f32x4 Ot[4] = {zero, zero, zero, zero};
  float mrun = -1e30f;
  float lsum = 0.f;

  // ---- prologue: stage K pair 0 -> slot 0, K pair 1 -> slot 1
  GLL(Ktiles + 0 * 4096 + t * 8, &KL[0][0][t * 8]);
  GLL(Ktiles + 1 * 4096 + t * 8, &KL[1][0][t * 8]);
  GLL(Ktiles + 2 * 4096 + t * 8, &KL[0][1][t * 8]);
  GLL(Ktiles + 3 * 4096 + t * 8, &KL[1][1][t * 8]);
  u64 a_cur = At[(size_t)kpar * NN + qrow];
  __syncthreads();

  // ---- prologue QK^T(0) -> stC (reads slot 0)
  f32x4 stC[4] = {zero, zero, zero, zero};
  {
    const char* kbase = (const char*)KL[kpar][0];
    __builtin_amdgcn_s_setprio(1);
    #pragma unroll
    for (int tk = 0; tk < 4; tk++) {
      int krow = tk * 16 + qi;
      #pragma unroll
      for (int dc = 0; dc < 2; dc++) {
        int off = (krow * 128 + (dc * 32 + g * 8) * 2) ^ ((krow & 7) << 4);
        short8 af = *(const short8*)(kbase + off);
        stC[tk] = __builtin_amdgcn_mfma_f32_16x16x32_bf16(af, qfrag[dc], stC[tk], 0, 0, 0);
      }
    }
    __builtin_amdgcn_s_setprio(0);
  }

  for (int i = 0; i < 32; i++) {
    // ---- top staging: K pair (i+2) -> ring slot (i+2)%3 ; V pair (i) -> VL
    if (i < 30) {
      const int slot = (i + 2) % 3;
      const size_t kt = 2 * (size_t)(i + 2);
      GLL(Ktiles + kt * 4096 + t * 8,       &KL[0][slot][t * 8]);
      GLL(Ktiles + (kt + 1) * 4096 + t * 8, &KL[1][slot][t * 8]);
    }
    {
      const size_t vt = 2 * (size_t)i;
      GLL(Vtiles + vt * 4096 + t * 8,       &VL[0][t * 8]);
      GLL(Vtiles + (vt + 1) * 4096 + t * 8, &VL[1][t * 8]);
    }
    u64 a_next = 0;
    if (i < 31) a_next = At[(size_t)(2 * (i + 1) + kpar) * NN + qrow];

    // ---- QK^T(i+1) -> stN (independent of softmax(i); MFMA completes in bg)
    f32x4 stN[4] = {zero, zero, zero, zero};
    if (i < 31) {
      const char* kbase = (const char*)KL[kpar][(i + 1) % 3];
      __builtin_amdgcn_s_setprio(1);
      #pragma unroll
      for (int tk = 0; tk < 4; tk++) {
        int krow = tk * 16 + qi;
        #pragma unroll
        for (int dc = 0; dc < 2; dc++) {
          int off = (krow * 128 + (dc * 32 + g * 8) * 2) ^ ((krow & 7) << 4);
          short8 af = *(const short8*)(kbase + off);
          stN[tk] = __builtin_amdgcn_mfma_f32_16x16x32_bf16(af, qfrag[dc], stN[tk], 0, 0, 0);
        }
      }
      __builtin_amdgcn_s_setprio(0);
    }

    u32 blo = (u32)a_cur, bhi = (u32)(a_cur >> 32);

    // ---- mask + tree max on stC  [R8 verbatim]
    #pragma unroll
    for (int tk = 0; tk < 4; tk++) {
      u32 half = (tk < 2) ? blo : bhi;
      int bb0 = (tk & 1) * 16 + g * 4;
      #pragma unroll
      for (int r = 0; r < 4; r++) {
        float s = stC[tk][r];
        stC[tk][r] = ((half >> (bb0 + r)) & 1u) ? s : -9e15f;
      }
    }
    float t0 = fmaxf(fmaxf(stC[0][0], stC[0][1]), fmaxf(stC[0][2], stC[0][3]));
    float t1 = fmaxf(fmaxf(stC[1][0], stC[1][1]), fmaxf(stC[1][2], stC[1][3]));
    float t2 = fmaxf(fmaxf(stC[2][0], stC[2][1]), fmaxf(stC[2][2], stC[2][3]));
    float t3 = fmaxf(fmaxf(stC[3][0], stC[3][1]), fmaxf(stC[3][2], stC[3][3]));
    float tmax = fmaxf(fmaxf(t0, t1), fmaxf(t2, t3));
    tmax = fmaxf(tmax, __shfl_xor(tmax, 16));
    tmax = fmaxf(tmax, __shfl_xor(tmax, 32));

    // ---- exact defer-max
    if (!__all(tmax <= mrun)) {
      const float newm = fmaxf(mrun, tmax);
      const float alpha = __builtin_amdgcn_exp2f(mrun - newm);
      lsum *= alpha;
      #pragma unroll
      for (int tv = 0; tv < 4; tv++) {
        Ot[tv][0] *= alpha; Ot[tv][1] *= alpha; Ot[tv][2] *= alpha; Ot[tv][3] *= alpha;
      }
      mrun = newm;
    }

    float psum = 0.f;
    u32 pk[8];
    #pragma unroll
    for (int tk = 0; tk < 4; tk++) {
      float p0 = __builtin_amdgcn_exp2f(stC[tk][0] - mrun);
      float p1 = __builtin_amdgcn_exp2f(stC[tk][1] - mrun);
      float p2 = __builtin_amdgcn_exp2f(stC[tk][2] - mrun);
      float p3 = __builtin_amdgcn_exp2f(stC[tk][3] - mrun);
      psum += (p0 + p1) + (p2 + p3);
      pk[tk * 2 + 0] = cvtpk(p0, p1);
      pk[tk * 2 + 1] = cvtpk(p2, p3);
    }
    psum += __shfl_xor(psum, 16);
    psum += __shfl_xor(psum, 32);
    lsum += psum;

    __syncthreads();   // V(i) staged & drained; all waves aligned

    // ---- redistribute P to B-frag layout + PV  [R8 verbatim; reads VL]
    const char* vbase = (const char*)VL[kpar];
    const int srcbase = qi + ((g & 1) << 5);
    #pragma unroll
    for (int kc = 0; kc < 2; kc++) {
      U4 pf;
      #pragma unroll
      for (int jp = 0; jp < 4; jp++) {
        int src = srcbase + ((jp >> 1) << 4);
        u32 va1 = (u32)__shfl((int)pk[4 * kc + (jp & 1)], src);
        u32 vb1 = (u32)__shfl((int)pk[4 * kc + 2 + (jp & 1)], src);
        pf.u[jp] = (g < 2) ? va1 : vb1;
      }
      __builtin_amdgcn_s_setprio(1);
      #pragma unroll
      for (int tv = 0; tv < 4; tv++) {
        int vd = tv * 16 + qi;
        int off = (vd * 128 + (kc * 32 + g * 8) * 2) ^ ((vd & 7) << 4);
        short8 vfrag = *(const short8*)(vbase + off);
        Ot[tv] = __builtin_amdgcn_mfma_f32_16x16x32_bf16(vfrag, pf.s, Ot[tv], 0, 0, 0);
      }
      __builtin_amdgcn_s_setprio(0);
    }

    __syncthreads();   // all PV reads of VL done -> next iter may overwrite VL

    // ---- rotate pipeline registers
    #pragma unroll
    for (int tk = 0; tk < 4; tk++) stC[tk] = stN[tk];
    a_cur = a_next;
  }

  // ---- merge the two k-parity partials (waves with same qh share q-rows)
  float* mb = (float*)&KL[0][0][0];            // scratch over KL (20 KB used)
  const int mbase = (qh * 64 + lane) * 20;
  if (kpar == 1) {
    #pragma unroll
    for (int tv = 0; tv < 4; tv++) {
      mb[mbase + tv * 4 + 0] = Ot[tv][0];
      mb[mbase + tv * 4 + 1] = Ot[tv][1];
      mb[mbase + tv * 4 + 2] = Ot[tv][2];
      mb[mbase + tv * 4 + 3] = Ot[tv][3];
    }
    mb[mbase + 16] = mrun;
    mb[mbase + 17] = lsum;
  }
  __syncthreads();
  if (kpar == 0) {
    const float m2 = mb[mbase + 16];
    const float l2 = mb[mbase + 17];
    const float M = fmaxf(mrun, m2);
    const float a1 = __builtin_amdgcn_exp2f(mrun - M);
    const float a2 = __builtin_amdgcn_exp2f(m2 - M);
    const float inv = 1.0f / (lsum * a1 + l2 * a2);
    #pragma unroll
    for (int tv = 0; tv < 4; tv++) {
      float4v o;
      o.x = (Ot[tv][0] * a1 + mb[mbase + tv * 4 + 0] * a2) * inv;
      o.y = (Ot[tv][1] * a1 + mb[mbase + tv * 4 + 1] * a2) * inv;
      o.z = (Ot[tv][2] * a1 + mb[mbase + tv * 4 + 2] * a2) * inv;
      o.w = (Ot[tv][3] * a1 + mb[mbase + tv * 4 + 3] * a2) * inv;
      *(float4v*)(out + (size_t)qrow * QKD + h * DD + tv * 16 + g * 4) = o;
    }
  }
}

// ============================================================================
// Fallback (no workspace): known-good round-1 kernel, f32 inputs in-kernel.
// ============================================================================
__global__ __launch_bounds__(512) void attn_fallback(
    const float* __restrict__ x1, const float* __restrict__ x2f,
    const float* __restrict__ vf, const int* __restrict__ adj,
    float* __restrict__ out)
{
  __shared__ u16 Klds[64 * 128];
  __shared__ u16 Vlds[128 * 64];
  __shared__ u64 Abits[64];

  const int b = blockIdx.x;
  const int qt = (b & 7) | ((b >> 5) << 3);
  const int hg = (b >> 3) & 3;
  const int h0 = hg * 2;
  const int t = threadIdx.x;
  const int w = t >> 6;
  const int lane = t & 63;
  const int qsub = w >> 1;
  const int hh = w & 1;
  const int h = h0 + hh;
  const int g = lane >> 4;
  const int qi = lane & 15;
  const int qbase = qt * 64;
  const int q_local = qsub * 16 + qi;
  const int qrow = qbase + q_local;

  const float SCL = 0.125f * 1.4426950408889634f;
  short8 qfrag[2];
  #pragma unroll
  for (int dc = 0; dc < 2; dc++) {
    const float* p = x1 + (size_t)qrow * QKD + h * DD + dc * 32 + g * 8;
    float4v a = *(const float4v*)p;
    float4v c = *(const float4v*)(p + 4);
    U8 r;
    r.u[0] = f2bf(a.x * SCL); r.u[1] = f2bf(a.y * SCL);
    r.u[2] = f2bf(a.z * SCL); r.u[3] = f2bf(a.w * SCL);
    r.u[4] = f2bf(c.x * SCL); r.u[5] = f2bf(c.y * SCL);
    r.u[6] = f2bf(c.z * SCL); r.u[7] = f2bf(c.w * SCL);
    qfrag[dc] = r.s;
  }

  const f32x4 zero = {0.f, 0.f, 0.f, 0.f};
  f32x4 Ot[4] = {zero, zero, zero, zero};
  float mrun = -1e30f;
  float lsum = 0.f;

  for (int kb = 0; kb < NN / 64; kb++) {
    const int k0 = kb * 64;
    __syncthreads();
    #pragma unroll
    for (int i = 0; i < 2; i++) {
      int s = t + i * 512;
      int row = s >> 4, c0 = (s & 15) * 8;
      int off = (row * 256 + c0 * 2) ^ ((row & 7) << 4);
      const float* p = x2f + (size_t)(k0 + row) * QKD + h0 * DD + c0;
      float4v a = *(const float4v*)p;
      float4v c = *(const float4v*)(p + 4);
      U8 r;
      r.u[0]=f2bf(a.x); r.u[1]=f2bf(a.y); r.u[2]=f2bf(a.z); r.u[3]=f2bf(a.w);
      r.u[4]=f2bf(c.x); r.u[5]=f2bf(c.y); r.u[6]=f2bf(c.z); r.u[7]=f2bf(c.w);
      *(short8*)((char*)Klds + off) = r.s;
    }
    {
      int vdg = t & 15, kp = t >> 4;
      int vd0 = vdg * 8, kk = kp * 2;
      u16 ua[8], ub[8];
      const float* pa = vf + (size_t)(k0 + kk) * QKD + h0 * DD + vd0;
      float4v a0 = *(const float4v*)pa;
      float4v a1 = *(const float4v*)(pa + 4);
      float4v b0 = *(const float4v*)(pa + QKD);
      float4v b1 = *(const float4v*)(pa + QKD + 4);
      ua[0]=f2bf(a0.x); ua[1]=f2bf(a0.y); ua[2]=f2bf(a0.z); ua[3]=f2bf(a0.w);
      ua[4]=f2bf(a1.x); ua[5]=f2bf(a1.y); ua[6]=f2bf(a1.z); ua[7]=f2bf(a1.w);
      ub[0]=f2bf(b0.x); ub[1]=f2bf(b0.y); ub[2]=f2bf(b0.z); ub[3]=f2bf(b0.w);
      ub[4]=f2bf(b1.x); ub[5]=f2bf(b1.y); ub[6]=f2bf(b1.z); ub[7]=f2bf(b1.w);
      #pragma unroll
      for (int j = 0; j < 8; j++) {
        u32 pk2 = (u32)ua[j] | ((u32)ub[j] << 16);
        int vd = vd0 + j;
        int off = (vd * 128 + kk * 2) ^ (((vd & 7) ^ ((vd >> 3) & 7)) << 4);
        *(u32*)((char*)Vlds + off) = pk2;
      }
    }
    {
      int row = t >> 3, c8 = t & 7;
      const int* ap = adj + (size_t)(qbase + row) * NN + k0 + c8 * 8;
      int4v a0 = *(const int4v*)ap;
      int4v a1 = *(const int4v*)(ap + 4);
      u32 byteval = (u32)(a0.x > 0)        | ((u32)(a0.y > 0) << 1) |
                    ((u32)(a0.z > 0) << 2) | ((u32)(a0.w > 0) << 3) |
                    ((u32)(a1.x > 0) << 4) | ((u32)(a1.y > 0) << 5) |
                    ((u32)(a1.z > 0) << 6) | ((u32)(a1.w > 0) << 7);
      ((unsigned char*)Abits)[row * 8 + c8] = (unsigned char)byteval;
    }
    __syncthreads();

    f32x4 st[4] = {zero, zero, zero, zero};
    #pragma unroll
    for (int tk = 0; tk < 4; tk++) {
      #pragma unroll
      for (int dc = 0; dc < 2; dc++) {
        int krow = tk * 16 + qi;
        int c = hh * 64 + dc * 32 + g * 8;
        int off = (krow * 256 + c * 2) ^ ((krow & 7) << 4);
        short8 af = *(const short8*)((char*)Klds + off);
        st[tk] = __builtin_amdgcn_mfma_f32_16x16x32_bf16(af, qfrag[dc], st[tk], 0, 0, 0);
      }
    }

    u64 bbm = Abits[q_local];
    u32 blo = (u32)bbm, bhi = (u32)(bbm >> 32);

    float tmax = -1e30f;
    #pragma unroll
    for (int tk = 0; tk < 4; tk++) {
      u32 half = (tk < 2) ? blo : bhi;
      int bb0 = (tk & 1) * 16 + g * 4;
      #pragma unroll
      for (int r = 0; r < 4; r++) {
        float s = st[tk][r];
        s = ((half >> (bb0 + r)) & 1u) ? s : -9e15f;
        st[tk][r] = s;
        tmax = fmaxf(tmax, s);
      }
    }
    tmax = fmaxf(tmax, __shfl_xor(tmax, 16));
    tmax = fmaxf(tmax, __shfl_xor(tmax, 32));
    float newm = fmaxf(mrun, tmax);
    float alpha = __builtin_amdgcn_exp2f(mrun - newm);
    mrun = newm;

    float psum = 0.f;
    u32 pk[8];
    #pragma unroll
    for (int tk = 0; tk < 4; tk++) {
      float p0 = __builtin_amdgcn_exp2f(st[tk][0] - newm);
      float p1 = __builtin_amdgcn_exp2f(st[tk][1] - newm);
      float p2 = __builtin_amdgcn_exp2f(st[tk][2] - newm);
      float p3 = __builtin_amdgcn_exp2f(st[tk][3] - newm);
      psum += (p0 + p1) + (p2 + p3);
      pk[tk * 2 + 0] = (u32)f2bf(p0) | ((u32)f2bf(p1) << 16);
      pk[tk * 2 + 1] = (u32)f2bf(p2) | ((u32)f2bf(p3) << 16);
    }
    psum += __shfl_xor(psum, 16);
    psum += __shfl_xor(psum, 32);
    lsum = lsum * alpha + psum;
    #pragma unroll
    for (int tv = 0; tv < 4; tv++) {
      Ot[tv][0] *= alpha; Ot[tv][1] *= alpha; Ot[tv][2] *= alpha; Ot[tv][3] *= alpha;
    }

    const int srcbase = qi + ((g & 1) << 5);
    #pragma unroll
    for (int kc = 0; kc < 2; kc++) {
      U4 pf;
      #pragma unroll
      for (int jp = 0; jp < 4; jp++) {
        int src = srcbase + ((jp >> 1) << 4);
        u32 va1 = (u32)__shfl((int)pk[4 * kc + (jp & 1)], src);
        u32 vb1 = (u32)__shfl((int)pk[4 * kc + 2 + (jp & 1)], src);
        pf.u[jp] = (g < 2) ? va1 : vb1;
      }
      #pragma unroll
      for (int tv = 0; tv < 4; tv++) {
        int vd = hh * 64 + tv * 16 + qi;
        int off = (vd * 128 + (kc * 32 + g * 8) * 2) ^ (((vd & 7) ^ ((vd >> 3) & 7)) << 4);
        short8 vfrag = *(const short8*)((char*)Vlds + off);
        Ot[tv] = __builtin_amdgcn_mfma_f32_16x16x32_bf16(vfrag, pf.s, Ot[tv], 0, 0, 0);
      }
    }
  }

  float inv = 1.0f / lsum;
  #pragma unroll
  for (int tv = 0; tv < 4; tv++) {
    float4v o;
    o.x = Ot[tv][0] * inv; o.y = Ot[tv][1] * inv;
    o.z = Ot[tv][2] * inv; o.w = Ot[tv][3] * inv;
    *(float4v*)(out + (size_t)qrow * QKD + h * DD + tv * 16 + g * 4) = o;
  }
}

extern "C" void kernel_launch(void* const* d_in, const int* in_sizes, int n_in,
                              void* d_out, int out_size, void* d_ws, size_t ws_size,
                              hipStream_t stream) {
  const float* x1 = (const float*)d_in[0];
  const float* x2 = (const float*)d_in[1];
  const float* v  = (const float*)d_in[2];
  const int* adj  = (const int*)d_in[3];
  float* out = (float*)d_out;

  const size_t szK = (size_t)512 * 4096 * sizeof(u16);     // 4 MB (512 tiles x 8KB)
  const size_t szV = szK;                                   // 4 MB
  const size_t szA = (size_t)NN * 64 * sizeof(u64);         // 2 MB
  const size_t need = szK + szV + szA;

  if (ws_size >= need && d_ws != nullptr) {
    u16* Kbt = (u16*)d_ws;
    u16* Vbt = (u16*)((char*)d_ws + szK);
    u64* At  = (u64*)((char*)d_ws + szK + szV);
    prepass_fused<<<dim3(5120), dim3(256), 0, stream>>>(x2, v, adj, Kbt, Vbt, At);
    attn_fast<<<dim3(512), dim3(512), 0, stream>>>(x1, At, Kbt, Vbt, out);
  } else {
    attn_fallback<<<dim3(256), dim3(512), 0, stream>>>(x1, x2, v, adj, out);
  }
}

// Round 11
// 195.617 us; speedup vs baseline: 1.0073x; 1.0073x over previous
//
#include <hip/hip_runtime.h>

#define NN 4096
#define HEADS 8
#define DD 64
#define QKD 512

typedef __attribute__((ext_vector_type(8))) short short8;
typedef __attribute__((ext_vector_type(4))) float f32x4;
typedef __attribute__((ext_vector_type(4))) float float4v;
typedef __attribute__((ext_vector_type(4))) int int4v;
typedef unsigned int u32;
typedef unsigned short u16;
typedef unsigned long long u64;

union U8 { u16 u[8]; short8 s; };
union U4 { u32 u[4]; short8 s; };

__device__ __forceinline__ u16 f2bf(float f) {
  u32 u = __float_as_uint(f);
  u += 0x7fffu + ((u >> 16) & 1u);   // RNE
  return (u16)(u >> 16);
}

__device__ __forceinline__ u32 cvtpk(float lo, float hi) {   // bf16(lo) | bf16(hi)<<16, RNE
  u32 d;
  asm("v_cvt_pk_bf16_f32 %0, %1, %2" : "=v"(d) : "v"(lo), "v"(hi));
  return d;
}

#define GLL(src, dst) __builtin_amdgcn_global_load_lds( \
    (const __attribute__((address_space(1))) void*)(src), \
    (__attribute__((address_space(3))) void*)(dst), 16, 0, 0)

// ============================================================================
// Fused prepass [R8 verbatim] (single launch, 5120 blocks x 256):
//   b in [0,4096):      adj row b -> TRANSPOSED bitmask At[tile*4096 + row] (u64)
//   b in [4096,4608):   x2 -> K bf16 tile images (pre-swizzled)
//   b in [4608,5120):   v  -> V^T bf16 tile images (pre-swizzled)
// K tile (h,kb), 8 KB:  I[off] = K[kb*64+kr][h*64+d],  off = kr*128 + (d*2 ^ ((kr&7)<<4))
// V tile (h,kb), 8 KB:  I[off] = V[kb*64+k ][h*64+vd], off = vd*128 + (k*2 ^ ((vd&7)<<4))
// ============================================================================
__global__ __launch_bounds__(256) void prepass_fused(
    const float* __restrict__ x2, const float* __restrict__ v,
    const int* __restrict__ adj,
    u16* __restrict__ Kbt, u16* __restrict__ Vbt, u64* __restrict__ At)
{
  __shared__ u16 Vtmp[64][80];
  const int b = blockIdx.x;
  const int t = threadIdx.x;

  if (b < 4096) {                      // ---------------- ADJ pack (1 row/block)
    const int row = b;
    const int* src = adj + (size_t)row * NN;
    int4v a0 = *(const int4v*)(src + t * 16);
    int4v a1 = *(const int4v*)(src + t * 16 + 4);
    int4v a2 = *(const int4v*)(src + t * 16 + 8);
    int4v a3 = *(const int4v*)(src + t * 16 + 12);
    u32 bits =
        (u32)(a0.x > 0)         | ((u32)(a0.y > 0) << 1)  |
        ((u32)(a0.z > 0) << 2)  | ((u32)(a0.w > 0) << 3)  |
        ((u32)(a1.x > 0) << 4)  | ((u32)(a1.y > 0) << 5)  |
        ((u32)(a1.z > 0) << 6)  | ((u32)(a1.w > 0) << 7)  |
        ((u32)(a2.x > 0) << 8)  | ((u32)(a2.y > 0) << 9)  |
        ((u32)(a2.z > 0) << 10) | ((u32)(a2.w > 0) << 11) |
        ((u32)(a3.x > 0) << 12) | ((u32)(a3.y > 0) << 13) |
        ((u32)(a3.z > 0) << 14) | ((u32)(a3.w > 0) << 15);
    unsigned char* AB = (unsigned char*)Vtmp;
    *(u16*)(AB + t * 2) = (u16)bits;
    __syncthreads();
    if (t < 64) {
      u64 m = *(const u64*)(AB + t * 8);      // word t = cols 64t..64t+63 (LE)
      At[(size_t)t * NN + row] = m;           // TRANSPOSED: [tile][row]
    }
  } else if (b < 4608) {               // ---------------- K tiles
    const int j = b - 4096;
    const int h = j >> 6, kb = j & 63;
    u16* dst = Kbt + (size_t)j * 4096;
    #pragma unroll
    for (int i = 0; i < 2; i++) {
      int c = t + i * 256;
      int off = c * 16;
      int kr = off >> 7;
      int db = (off & 127) ^ ((kr & 7) << 4);
      int d0 = db >> 1;
      const float* p = x2 + (size_t)(kb * 64 + kr) * QKD + h * DD + d0;
      float4v a0 = *(const float4v*)p;
      float4v a1 = *(const float4v*)(p + 4);
      U8 r;
      r.u[0] = f2bf(a0.x); r.u[1] = f2bf(a0.y); r.u[2] = f2bf(a0.z); r.u[3] = f2bf(a0.w);
      r.u[4] = f2bf(a1.x); r.u[5] = f2bf(a1.y); r.u[6] = f2bf(a1.z); r.u[7] = f2bf(a1.w);
      *(short8*)((char*)dst + off) = r.s;
    }
  } else {                             // ---------------- V tiles (transpose via LDS)
    const int bb = b - 4608;
    const int h = bb >> 6, kb = bb & 63;
    {
      int k = t >> 2, j0 = (t & 3) * 16;
      const float* p = v + (size_t)(kb * 64 + k) * QKD + h * DD + j0;
      float4v a0 = *(const float4v*)p;
      float4v a1 = *(const float4v*)(p + 4);
      float4v a2 = *(const float4v*)(p + 8);
      float4v a3 = *(const float4v*)(p + 12);
      U8 r0, r1;
      r0.u[0] = f2bf(a0.x); r0.u[1] = f2bf(a0.y); r0.u[2] = f2bf(a0.z); r0.u[3] = f2bf(a0.w);
      r0.u[4] = f2bf(a1.x); r0.u[5] = f2bf(a1.y); r0.u[6] = f2bf(a1.z); r0.u[7] = f2bf(a1.w);
      r1.u[0] = f2bf(a2.x); r1.u[1] = f2bf(a2.y); r1.u[2] = f2bf(a2.z); r1.u[3] = f2bf(a2.w);
      r1.u[4] = f2bf(a3.x); r1.u[5] = f2bf(a3.y); r1.u[6] = f2bf(a3.z); r1.u[7] = f2bf(a3.w);
      *(short8*)(&Vtmp[k][j0]) = r0.s;
      *(short8*)(&Vtmp[k][j0 + 8]) = r1.s;
    }
    __syncthreads();
    u16* dst = Vbt + (size_t)bb * 4096;
    #pragma unroll
    for (int i = 0; i < 2; i++) {
      int c = t + i * 256;
      int off = c * 16;
      int vd = off >> 7;
      int kbyte = (off & 127) ^ ((vd & 7) << 4);
      int k0 = kbyte >> 1;
      U8 r;
      #pragma unroll
      for (int jj = 0; jj < 8; jj++) r.u[jj] = Vtmp[k0 + jj][vd];
      *(short8*)((char*)dst + off) = r.s;
    }
  }
}

// ============================================================================
// Main fused kernel. R10 body with SINGLE barrier per iteration:
//   V double-buffered and staged ONE ITER AHEAD (iter i stages V(i+1) into
//   vbuf (i+1)&1; PV(i) reads vbuf i&1 — staged at iter i-1, drained by the
//   end-of-(i-1) barrier). K: 3-slot ring as R10. One __syncthreads per iter,
//   draining only loads issued a full iteration earlier.
// Lifetimes: vbuf[b] read at iter i (pre-barrier), rewritten at iter i+1
// (post-barrier(i)) -> 1 barrier between. K slot s: read iter t-1, rewritten
// iter t+1 -> 2 barriers between.
// LDS 80 KB/block -> 2 blocks/CU (160 KB = full CU budget).
// Grid 512 (h = b&7: per-XCD single head), 512 thr = 4 q-waves x 2 k-parities.
// ============================================================================
__global__ __launch_bounds__(512, 4) void attn_fast(
    const float* __restrict__ x1,
    const u64* __restrict__ At,
    const u16* __restrict__ Kbt, const u16* __restrict__ Vbt,
    float* __restrict__ out)
{
  __shared__ u16 KL[2][3][4096];   // [kpar][ring slot][8KB tile image]  48 KB
  __shared__ u16 VL[2][2][4096];   // [kpar][buf][8KB tile image]        32 KB

  const int b = blockIdx.x;
  const int h = b & 7;             // XCD-head affinity
  const int qt = b >> 3;
  const int t = threadIdx.x;
  const int w = t >> 6;
  const int lane = t & 63;
  const int g = lane >> 4;
  const int qi = lane & 15;
  const int qh = w & 3;
  const int kpar = w >> 2;
  const int qrow = qt * 64 + qh * 16 + qi;

  const u16* Ktiles = Kbt + (size_t)h * 64 * 4096;
  const u16* Vtiles = Vbt + (size_t)h * 64 * 4096;

  const float SCL = 0.125f * 1.4426950408889634f;
  short8 qfrag[2];
  #pragma unroll
  for (int dc = 0; dc < 2; dc++) {
    const float* p = x1 + (size_t)qrow * QKD + h * DD + dc * 32 + g * 8;
    float4v a = *(const float4v*)p;
    float4v c = *(const float4v*)(p + 4);
    U8 r;
    r.u[0] = f2bf(a.x * SCL); r.u[1] = f2bf(a.y * SCL);
    r.u[2] = f2bf(a.z * SCL); r.u[3] = f2bf(a.w * SCL);
    r.u[4] = f2bf(c.x * SCL); r.u[5] = f2bf(c.y * SCL);
    r.u[6] = f2bf(c.z * SCL); r.u[7] = f2bf(c.w * SCL);
    qfrag[dc] = r.s;
  }

  const f32x4 zero = {0.f, 0.f, 0.f, 0.f};
  f32x4 Ot[4] = {zero, zero, zero, zero};
  float mrun = -1e30f;
  float lsum = 0.f;

  // ---- prologue: K pair 0 -> slot 0, K pair 1 -> slot 1, V pair 0 -> vbuf 0
  GLL(Ktiles + 0 * 4096 + t * 8, &KL[0][0][t * 8]);
  GLL(Ktiles + 1 * 4096 + t * 8, &KL[1][0][t * 8]);
  GLL(Ktiles + 2 * 4096 + t * 8, &KL[0][1][t * 8]);
  GLL(Ktiles + 3 * 4096 + t * 8, &KL[1][1][t * 8]);
  GLL(Vtiles + 0 * 4096 + t * 8, &VL[0][0][t * 8]);
  GLL(Vtiles + 1 * 4096 + t * 8, &VL[1][0][t * 8]);
  u64 a_cur = At[(size_t)kpar * NN + qrow];
  __syncthreads();

  // ---- prologue QK^T(0) -> stC (reads K slot 0)
  f32x4 stC[4] = {zero, zero, zero, zero};
  {
    const char* kbase = (const char*)KL[kpar][0];
    __builtin_amdgcn_s_setprio(1);
    #pragma unroll
    for (int tk = 0; tk < 4; tk++) {
      int krow = tk * 16 + qi;
      #pragma unroll
      for (int dc = 0; dc < 2; dc++) {
        int off = (krow * 128 + (dc * 32 + g * 8) * 2) ^ ((krow & 7) << 4);
        short8 af = *(const short8*)(kbase + off);
        stC[tk] = __builtin_amdgcn_mfma_f32_16x16x32_bf16(af, qfrag[dc], stC[tk], 0, 0, 0);
      }
    }
    __builtin_amdgcn_s_setprio(0);
  }

  for (int i = 0; i < 32; i++) {
    // ---- staging: K pair (i+2) -> ring slot (i+2)%3 ; V pair (i+1) -> vbuf (i+1)&1
    if (i < 30) {
      const int slot = (i + 2) % 3;
      const size_t kt = 2 * (size_t)(i + 2);
      GLL(Ktiles + kt * 4096 + t * 8,       &KL[0][slot][t * 8]);
      GLL(Ktiles + (kt + 1) * 4096 + t * 8, &KL[1][slot][t * 8]);
    }
    if (i < 31) {
      const int nb = (i + 1) & 1;
      const size_t vt = 2 * (size_t)(i + 1);
      GLL(Vtiles + vt * 4096 + t * 8,       &VL[0][nb][t * 8]);
      GLL(Vtiles + (vt + 1) * 4096 + t * 8, &VL[1][nb][t * 8]);
    }
    u64 a_next = 0;
    if (i < 31) a_next = At[(size_t)(2 * (i + 1) + kpar) * NN + qrow];

    // ---- QK^T(i+1) -> stN (reads K slot (i+1)%3, staged at iter i-1)
    f32x4 stN[4] = {zero, zero, zero, zero};
    if (i < 31) {
      const char* kbase = (const char*)KL[kpar][(i + 1) % 3];
      __builtin_amdgcn_s_setprio(1);
      #pragma unroll
      for (int tk = 0; tk < 4; tk++) {
        int krow = tk * 16 + qi;
        #pragma unroll
        for (int dc = 0; dc < 2; dc++) {
          int off = (krow * 128 + (dc * 32 + g * 8) * 2) ^ ((krow & 7) << 4);
          short8 af = *(const short8*)(kbase + off);
          stN[tk] = __builtin_amdgcn_mfma_f32_16x16x32_bf16(af, qfrag[dc], stN[tk], 0, 0, 0);
        }
      }
      __builtin_amdgcn_s_setprio(0);
    }

    u32 blo = (u32)a_cur, bhi = (u32)(a_cur >> 32);

    // ---- mask + tree max on stC
    #pragma unroll
    for (int tk = 0; tk < 4; tk++) {
      u32 half = (tk < 2) ? blo : bhi;
      int bb0 = (tk & 1) * 16 + g * 4;
      #pragma unroll
      for (int r = 0; r < 4; r++) {
        float s = stC[tk][r];
        stC[tk][r] = ((half >> (bb0 + r)) & 1u) ? s : -9e15f;
      }
    }
    float t0 = fmaxf(fmaxf(stC[0][0], stC[0][1]), fmaxf(stC[0][2], stC[0][3]));
    float t1 = fmaxf(fmaxf(stC[1][0], stC[1][1]), fmaxf(stC[1][2], stC[1][3]));
    float t2 = fmaxf(fmaxf(stC[2][0], stC[2][1]), fmaxf(stC[2][2], stC[2][3]));
    float t3 = fmaxf(fmaxf(stC[3][0], stC[3][1]), fmaxf(stC[3][2], stC[3][3]));
    float tmax = fmaxf(fmaxf(t0, t1), fmaxf(t2, t3));
    tmax = fmaxf(tmax, __shfl_xor(tmax, 16));
    tmax = fmaxf(tmax, __shfl_xor(tmax, 32));

    // ---- exact defer-max
    if (!__all(tmax <= mrun)) {
      const float newm = fmaxf(mrun, tmax);
      const float alpha = __builtin_amdgcn_exp2f(mrun - newm);
      lsum *= alpha;
      #pragma unroll
      for (int tv = 0; tv < 4; tv++) {
        Ot[tv][0] *= alpha; Ot[tv][1] *= alpha; Ot[tv][2] *= alpha; Ot[tv][3] *= alpha;
      }
      mrun = newm;
    }

    float psum = 0.f;
    u32 pk[8];
    #pragma unroll
    for (int tk = 0; tk < 4; tk++) {
      float p0 = __builtin_amdgcn_exp2f(stC[tk][0] - mrun);
      float p1 = __builtin_amdgcn_exp2f(stC[tk][1] - mrun);
      float p2 = __builtin_amdgcn_exp2f(stC[tk][2] - mrun);
      float p3 = __builtin_amdgcn_exp2f(stC[tk][3] - mrun);
      psum += (p0 + p1) + (p2 + p3);
      pk[tk * 2 + 0] = cvtpk(p0, p1);
      pk[tk * 2 + 1] = cvtpk(p2, p3);
    }
    psum += __shfl_xor(psum, 16);
    psum += __shfl_xor(psum, 32);
    lsum += psum;

    // ---- redistribute P to B-frag layout + PV (reads vbuf i&1, staged iter i-1)
    const char* vbase = (const char*)VL[kpar][i & 1];
    const int srcbase = qi + ((g & 1) << 5);
    #pragma unroll
    for (int kc = 0; kc < 2; kc++) {
      U4 pf;
      #pragma unroll
      for (int jp = 0; jp < 4; jp++) {
        int src = srcbase + ((jp >> 1) << 4);
        u32 va1 = (u32)__shfl((int)pk[4 * kc + (jp & 1)], src);
        u32 vb1 = (u32)__shfl((int)pk[4 * kc + 2 + (jp & 1)], src);
        pf.u[jp] = (g < 2) ? va1 : vb1;
      }
      __builtin_amdgcn_s_setprio(1);
      #pragma unroll
      for (int tv = 0; tv < 4; tv++) {
        int vd = tv * 16 + qi;
        int off = (vd * 128 + (kc * 32 + g * 8) * 2) ^ ((vd & 7) << 4);
        short8 vfrag = *(const short8*)(vbase + off);
        Ot[tv] = __builtin_amdgcn_mfma_f32_16x16x32_bf16(vfrag, pf.s, Ot[tv], 0, 0, 0);
      }
      __builtin_amdgcn_s_setprio(0);
    }

    __syncthreads();   // single barrier: drains loads issued a full iter ago

    // ---- rotate pipeline registers
    #pragma unroll
    for (int tk = 0; tk < 4; tk++) stC[tk] = stN[tk];
    a_cur = a_next;
  }

  // ---- merge the two k-parity partials (waves with same qh share q-rows)
  float* mb = (float*)&KL[0][0][0];            // scratch over KL (20 KB used)
  const int mbase = (qh * 64 + lane) * 20;
  if (kpar == 1) {
    #pragma unroll
    for (int tv = 0; tv < 4; tv++) {
      mb[mbase + tv * 4 + 0] = Ot[tv][0];
      mb[mbase + tv * 4 + 1] = Ot[tv][1];
      mb[mbase + tv * 4 + 2] = Ot[tv][2];
      mb[mbase + tv * 4 + 3] = Ot[tv][3];
    }
    mb[mbase + 16] = mrun;
    mb[mbase + 17] = lsum;
  }
  __syncthreads();
  if (kpar == 0) {
    const float m2 = mb[mbase + 16];
    const float l2 = mb[mbase + 17];
    const float M = fmaxf(mrun, m2);
    const float a1 = __builtin_amdgcn_exp2f(mrun - M);
    const float a2 = __builtin_amdgcn_exp2f(m2 - M);
    const float inv = 1.0f / (lsum * a1 + l2 * a2);
    #pragma unroll
    for (int tv = 0; tv < 4; tv++) {
      float4v o;
      o.x = (Ot[tv][0] * a1 + mb[mbase + tv * 4 + 0] * a2) * inv;
      o.y = (Ot[tv][1] * a1 + mb[mbase + tv * 4 + 1] * a2) * inv;
      o.z = (Ot[tv][2] * a1 + mb[mbase + tv * 4 + 2] * a2) * inv;
      o.w = (Ot[tv][3] * a1 + mb[mbase + tv * 4 + 3] * a2) * inv;
      *(float4v*)(out + (size_t)qrow * QKD + h * DD + tv * 16 + g * 4) = o;
    }
  }
}

// ============================================================================
// Fallback (no workspace): known-good round-1 kernel, f32 inputs in-kernel.
// ============================================================================
__global__ __launch_bounds__(512) void attn_fallback(
    const float* __restrict__ x1, const float* __restrict__ x2f,
    const float* __restrict__ vf, const int* __restrict__ adj,
    float* __restrict__ out)
{
  __shared__ u16 Klds[64 * 128];
  __shared__ u16 Vlds[128 * 64];
  __shared__ u64 Abits[64];

  const int b = blockIdx.x;
  const int qt = (b & 7) | ((b >> 5) << 3);
  const int hg = (b >> 3) & 3;
  const int h0 = hg * 2;
  const int t = threadIdx.x;
  const int w = t >> 6;
  const int lane = t & 63;
  const int qsub = w >> 1;
  const int hh = w & 1;
  const int h = h0 + hh;
  const int g = lane >> 4;
  const int qi = lane & 15;
  const int qbase = qt * 64;
  const int q_local = qsub * 16 + qi;
  const int qrow = qbase + q_local;

  const float SCL = 0.125f * 1.4426950408889634f;
  short8 qfrag[2];
  #pragma unroll
  for (int dc = 0; dc < 2; dc++) {
    const float* p = x1 + (size_t)qrow * QKD + h * DD + dc * 32 + g * 8;
    float4v a = *(const float4v*)p;
    float4v c = *(const float4v*)(p + 4);
    U8 r;
    r.u[0] = f2bf(a.x * SCL); r.u[1] = f2bf(a.y * SCL);
    r.u[2] = f2bf(a.z * SCL); r.u[3] = f2bf(a.w * SCL);
    r.u[4] = f2bf(c.x * SCL); r.u[5] = f2bf(c.y * SCL);
    r.u[6] = f2bf(c.z * SCL); r.u[7] = f2bf(c.w * SCL);
    qfrag[dc] = r.s;
  }

  const f32x4 zero = {0.f, 0.f, 0.f, 0.f};
  f32x4 Ot[4] = {zero, zero, zero, zero};
  float mrun = -1e30f;
  float lsum = 0.f;

  for (int kb = 0; kb < NN / 64; kb++) {
    const int k0 = kb * 64;
    __syncthreads();
    #pragma unroll
    for (int i = 0; i < 2; i++) {
      int s = t + i * 512;
      int row = s >> 4, c0 = (s & 15) * 8;
      int off = (row * 256 + c0 * 2) ^ ((row & 7) << 4);
      const float* p = x2f + (size_t)(k0 + row) * QKD + h0 * DD + c0;
      float4v a = *(const float4v*)p;
      float4v c = *(const float4v*)(p + 4);
      U8 r;
      r.u[0]=f2bf(a.x); r.u[1]=f2bf(a.y); r.u[2]=f2bf(a.z); r.u[3]=f2bf(a.w);
      r.u[4]=f2bf(c.x); r.u[5]=f2bf(c.y); r.u[6]=f2bf(c.z); r.u[7]=f2bf(c.w);
      *(short8*)((char*)Klds + off) = r.s;
    }
    {
      int vdg = t & 15, kp = t >> 4;
      int vd0 = vdg * 8, kk = kp * 2;
      u16 ua[8], ub[8];
      const float* pa = vf + (size_t)(k0 + kk) * QKD + h0 * DD + vd0;
      float4v a0 = *(const float4v*)pa;
      float4v a1 = *(const float4v*)(pa + 4);
      float4v b0 = *(const float4v*)(pa + QKD);
      float4v b1 = *(const float4v*)(pa + QKD + 4);
      ua[0]=f2bf(a0.x); ua[1]=f2bf(a0.y); ua[2]=f2bf(a0.z); ua[3]=f2bf(a0.w);
      ua[4]=f2bf(a1.x); ua[5]=f2bf(a1.y); ua[6]=f2bf(a1.z); ua[7]=f2bf(a1.w);
      ub[0]=f2bf(b0.x); ub[1]=f2bf(b0.y); ub[2]=f2bf(b0.z); ub[3]=f2bf(b0.w);
      ub[4]=f2bf(b1.x); ub[5]=f2bf(b1.y); ub[6]=f2bf(b1.z); ub[7]=f2bf(b1.w);
      #pragma unroll
      for (int j = 0; j < 8; j++) {
        u32 pk2 = (u32)ua[j] | ((u32)ub[j] << 16);
        int vd = vd0 + j;
        int off = (vd * 128 + kk * 2) ^ (((vd & 7) ^ ((vd >> 3) & 7)) << 4);
        *(u32*)((char*)Vlds + off) = pk2;
      }
    }
    {
      int row = t >> 3, c8 = t & 7;
      const int* ap = adj + (size_t)(qbase + row) * NN + k0 + c8 * 8;
      int4v a0 = *(const int4v*)ap;
      int4v a1 = *(const int4v*)(ap + 4);
      u32 byteval = (u32)(a0.x > 0)        | ((u32)(a0.y > 0) << 1) |
                    ((u32)(a0.z > 0) << 2) | ((u32)(a0.w > 0) << 3) |
                    ((u32)(a1.x > 0) << 4) | ((u32)(a1.y > 0) << 5) |
                    ((u32)(a1.z > 0) << 6) | ((u32)(a1.w > 0) << 7);
      ((unsigned char*)Abits)[row * 8 + c8] = (unsigned char)byteval;
    }
    __syncthreads();

    f32x4 st[4] = {zero, zero, zero, zero};
    #pragma unroll
    for (int tk = 0; tk < 4; tk++) {
      #pragma unroll
      for (int dc = 0; dc < 2; dc++) {
        int krow = tk * 16 + qi;
        int c = hh * 64 + dc * 32 + g * 8;
        int off = (krow * 256 + c * 2) ^ ((krow & 7) << 4);
        short8 af = *(const short8*)((char*)Klds + off);
        st[tk] = __builtin_amdgcn_mfma_f32_16x16x32_bf16(af, qfrag[dc], st[tk], 0, 0, 0);
      }
    }

    u64 bbm = Abits[q_local];
    u32 blo = (u32)bbm, bhi = (u32)(bbm >> 32);

    float tmax = -1e30f;
    #pragma unroll
    for (int tk = 0; tk < 4; tk++) {
      u32 half = (tk < 2) ? blo : bhi;
      int bb0 = (tk & 1) * 16 + g * 4;
      #pragma unroll
      for (int r = 0; r < 4; r++) {
        float s = st[tk][r];
        s = ((half >> (bb0 + r)) & 1u) ? s : -9e15f;
        st[tk][r] = s;
        tmax = fmaxf(tmax, s);
      }
    }
    tmax = fmaxf(tmax, __shfl_xor(tmax, 16));
    tmax = fmaxf(tmax, __shfl_xor(tmax, 32));
    float newm = fmaxf(mrun, tmax);
    float alpha = __builtin_amdgcn_exp2f(mrun - newm);
    mrun = newm;

    float psum = 0.f;
    u32 pk[8];
    #pragma unroll
    for (int tk = 0; tk < 4; tk++) {
      float p0 = __builtin_amdgcn_exp2f(st[tk][0] - newm);
      float p1 = __builtin_amdgcn_exp2f(st[tk][1] - newm);
      float p2 = __builtin_amdgcn_exp2f(st[tk][2] - newm);
      float p3 = __builtin_amdgcn_exp2f(st[tk][3] - newm);
      psum += (p0 + p1) + (p2 + p3);
      pk[tk * 2 + 0] = (u32)f2bf(p0) | ((u32)f2bf(p1) << 16);
      pk[tk * 2 + 1] = (u32)f2bf(p2) | ((u32)f2bf(p3) << 16);
    }
    psum += __shfl_xor(psum, 16);
    psum += __shfl_xor(psum, 32);
    lsum = lsum * alpha + psum;
    #pragma unroll
    for (int tv = 0; tv < 4; tv++) {
      Ot[tv][0] *= alpha; Ot[tv][1] *= alpha; Ot[tv][2] *= alpha; Ot[tv][3] *= alpha;
    }

    const int srcbase = qi + ((g & 1) << 5);
    #pragma unroll
    for (int kc = 0; kc < 2; kc++) {
      U4 pf;
      #pragma unroll
      for (int jp = 0; jp < 4; jp++) {
        int src = srcbase + ((jp >> 1) << 4);
        u32 va1 = (u32)__shfl((int)pk[4 * kc + (jp & 1)], src);
        u32 vb1 = (u32)__shfl((int)pk[4 * kc + 2 + (jp & 1)], src);
        pf.u[jp] = (g < 2) ? va1 : vb1;
      }
      #pragma unroll
      for (int tv = 0; tv < 4; tv++) {
        int vd = hh * 64 + tv * 16 + qi;
        int off = (vd * 128 + (kc * 32 + g * 8) * 2) ^ (((vd & 7) ^ ((vd >> 3) & 7)) << 4);
        short8 vfrag = *(const short8*)((char*)Vlds + off);
        Ot[tv] = __builtin_amdgcn_mfma_f32_16x16x32_bf16(vfrag, pf.s, Ot[tv], 0, 0, 0);
      }
    }
  }

  float inv = 1.0f / lsum;
  #pragma unroll
  for (int tv = 0; tv < 4; tv++) {
    float4v o;
    o.x = Ot[tv][0] * inv; o.y = Ot[tv][1] * inv;
    o.z = Ot[tv][2] * inv; o.w = Ot[tv][3] * inv;
    *(float4v*)(out + (size_t)qrow * QKD + h * DD + tv * 16 + g * 4) = o;
  }
}

extern "C" void kernel_launch(void* const* d_in, const int* in_sizes, int n_in,
                              void* d_out, int out_size, void* d_ws, size_t ws_size,
                              hipStream_t stream) {
  const float* x1 = (const float*)d_in[0];
  const float* x2 = (const float*)d_in[1];
  const float* v  = (const float*)d_in[2];
  const int* adj  = (const int*)d_in[3];
  float* out = (float*)d_out;

  const size_t szK = (size_t)512 * 4096 * sizeof(u16);     // 4 MB (512 tiles x 8KB)
  const size_t szV = szK;                                   // 4 MB
  const size_t szA = (size_t)NN * 64 * sizeof(u64);         // 2 MB
  const size_t need = szK + szV + szA;

  if (ws_size >= need && d_ws != nullptr) {
    u16* Kbt = (u16*)d_ws;
    u16* Vbt = (u16*)((char*)d_ws + szK);
    u64* At  = (u64*)((char*)d_ws + szK + szV);
    prepass_fused<<<dim3(5120), dim3(256), 0, stream>>>(x2, v, adj, Kbt, Vbt, At);
    attn_fast<<<dim3(512), dim3(512), 0, stream>>>(x1, At, Kbt, Vbt, out);
  } else {
    attn_fallback<<<dim3(256), dim3(512), 0, stream>>>(x1, x2, v, adj, out);
  }
}